// Round 3
// baseline (969.587 us; speedup 1.0000x reference)
//
#include <hip/hip_runtime.h>
#include <math.h>

#define DD 64
#define HH 128

typedef __attribute__((ext_vector_type(8))) short bf16x8;
typedef __attribute__((ext_vector_type(4))) short s16x4;
typedef __attribute__((ext_vector_type(4))) float f32x4;
typedef __attribute__((ext_vector_type(4))) int i32x4;

__device__ __forceinline__ short f2bf(float x){
    unsigned u = __builtin_bit_cast(unsigned, x);
    u += 0x7fffu + ((u >> 16) & 1u);          // RTNE
    return (short)(u >> 16);
}
__device__ __forceinline__ float bf2f(short s){
    unsigned u = ((unsigned)(unsigned short)s) << 16;
    return __builtin_bit_cast(float, u);
}
__device__ __forceinline__ float fast_tanh(float x){
    float e = __expf(2.0f * x);
    return 1.0f - 2.0f / (e + 1.0f);
}
__device__ __forceinline__ float elu1(float x){
    return x > 0.0f ? x : (__expf(x) - 1.0f);
}

// histogram of dst (int) for both graphs + h -> bf16 conversion
__global__ __launch_bounds__(256) void hist_conv(
    const int* __restrict__ dst1, const int* __restrict__ dst2,
    const float* __restrict__ h,
    int* __restrict__ cnt1, int* __restrict__ cnt2,
    short* __restrict__ h_bf, int E, int Nq) {
    int tid = blockIdx.x * 256 + threadIdx.x;
    if (tid < E) {
        atomicAdd(&cnt1[dst1[tid]], 1);
        atomicAdd(&cnt2[dst2[tid]], 1);
    }
    if (tid < Nq) {
        float4 v = ((const float4*)h)[tid];
        s16x4 o;
        o[0] = f2bf(v.x); o[1] = f2bf(v.y); o[2] = f2bf(v.z); o[3] = f2bf(v.w);
        ((s16x4*)h_bf)[tid] = o;
    }
}

// exclusive prefix sum of cnt -> off. block 0: graph1, block 1: graph2.
__global__ __launch_bounds__(1024) void scan2(
    const int* __restrict__ c1, int* __restrict__ o1,
    const int* __restrict__ c2, int* __restrict__ o2, int n) {
    const int* cnt = blockIdx.x ? c2 : c1;
    int* off       = blockIdx.x ? o2 : o1;
    __shared__ int ssum[1024];
    int tid = threadIdx.x;
    int per = (n + 1023) >> 10;
    int lo = tid * per;
    int hi = lo + per; if (hi > n) hi = n;
    int s = 0;
    for (int i = lo; i < hi; i++) s += cnt[i];
    ssum[tid] = s;
    __syncthreads();
    for (int d = 1; d < 1024; d <<= 1) {
        int t = (tid >= d) ? ssum[tid - d] : 0;
        __syncthreads();
        ssum[tid] += t;
        __syncthreads();
    }
    int run = ssum[tid] - s;     // exclusive prefix of this chunk
    for (int i = lo; i < hi; i++) { off[i] = run; run += cnt[i]; }
}

// scatter edge src ids into dst-sorted order (4B per edge instead of 256B rows)
__global__ __launch_bounds__(256) void esort(
    const int* __restrict__ src1, const int* __restrict__ dst1,
    const int* __restrict__ src2, const int* __restrict__ dst2,
    int* __restrict__ off1, int* __restrict__ off2,
    int* __restrict__ eidx1, int* __restrict__ eidx2, int E) {
    int e = blockIdx.x * 256 + threadIdx.x;
    if (e >= E) return;
    { int d = dst1[e]; int pos = atomicAdd(&off1[d], 1); eidx1[pos] = src1[e]; }
    { int d = dst2[e]; int pos = atomicAdd(&off2[d], 1); eidx2[pos] = src2[e]; }
}

// wave per (graph,node): sum in-edge h[src] rows in registers, scale by 1/deg, write bf16 row
__global__ __launch_bounds__(256) void gather(
    const float* __restrict__ h,
    const int* __restrict__ cnt1, const int* __restrict__ off1,
    const int* __restrict__ eidx1, short* __restrict__ a1bf,
    const int* __restrict__ cnt2, const int* __restrict__ off2,
    const int* __restrict__ eidx2, short* __restrict__ a2bf, int N) {
    int w = blockIdx.x * 4 + (threadIdx.x >> 6);
    int lane = threadIdx.x & 63;
    if (w >= 2 * N) return;
    int g = w >= N;
    int n = g ? w - N : w;
    const int* cnt  = g ? cnt2  : cnt1;
    const int* off  = g ? off2  : off1;
    const int* eidx = g ? eidx2 : eidx1;
    short* abf      = g ? a2bf  : a1bf;

    int end = off[n];            // off was advanced to end by esort
    int deg = cnt[n];
    int i = end - deg;
    float acc = 0.f;
    for (; i + 1 < end; i += 2) {
        int s0 = eidx[i], s1 = eidx[i + 1];
        float v0 = h[(size_t)s0 * DD + lane];
        float v1 = h[(size_t)s1 * DD + lane];
        acc += v0 + v1;
    }
    if (i < end) acc += h[(size_t)eidx[i] * DD + lane];
    float inv = deg > 0 ? 1.f / (float)deg : 0.f;
    abf[(size_t)n * DD + lane] = f2bf(acc * inv);
}

// MFMA fused kernel: wave = 16 nodes, block = 64 nodes, persistent grid.
// GEMM1: z0 = h@W_id+b, z1 = elu(a1@W1+b1), z2 = elu(a2@W2+b2)
// GEMM2: t = z@Wp1+bp1; wsum_p += sum(tanh(t)*Wp2)
// z bf16: zbuf1 row n (256B) = [z1 | z0], zbuf2 row n (128B) = [z2]
__global__ __launch_bounds__(256, 2) void fuse_kernel(
    const short* __restrict__ h_bf,
    const float* __restrict__ W_id, const float* __restrict__ b_id,
    const float* __restrict__ W1, const float* __restrict__ b1,
    const float* __restrict__ W2, const float* __restrict__ b2,
    const float* __restrict__ Wp1, const float* __restrict__ bp1,
    const float* __restrict__ Wp2,
    const short* __restrict__ a1bf, const short* __restrict__ a2bf,
    short* __restrict__ zbuf1, short* __restrict__ zbuf2,
    float* __restrict__ w_acc, int N)
{
    __shared__ __align__(16) short sWb[12288];  // 3 paths * 4 ct * 2 ks * 512
    __shared__ __align__(16) short sWp[8192];   // 8 ct * 2 ks * 512
    __shared__ __align__(16) short sZ[4][3072]; // per wave: 3 paths * 2 ks * 512 (A-frag order)

    for (int i = threadIdx.x; i < 12288; i += 256) {
        int p = i >> 12, r = i & 4095;
        int ct = r >> 10, rr = r & 1023;
        int ks = rr >> 9, q = rr & 511;
        int ln = q >> 3, j = q & 7;
        int c = ct * 16 + (ln & 15);
        int k = ks * 32 + (ln >> 4) * 8 + j;
        int idx = k * DD + c;
        float v = (p == 0) ? W_id[idx] : (p == 1 ? W1[idx] : W2[idx]);
        sWb[i] = f2bf(v);
    }
    for (int i = threadIdx.x; i < 8192; i += 256) {
        int ct = i >> 10, rr = i & 1023;
        int ks = rr >> 9, q = rr & 511;
        int ln = q >> 3, j = q & 7;
        int c = ct * 16 + (ln & 15);
        int k = ks * 32 + (ln >> 4) * 8 + j;
        sWp[i] = f2bf(Wp1[k * HH + c]);
    }

    int lane = threadIdx.x & 63;
    int wv = threadIdx.x >> 6;
    int cl = lane & 15;
    int quad = lane >> 4;

    float bid[4], bb1r[4], bb2r[4];
    #pragma unroll
    for (int ct = 0; ct < 4; ct++) {
        bid[ct]  = b_id[ct*16 + cl];
        bb1r[ct] = b1[ct*16 + cl];
        bb2r[ct] = b2[ct*16 + cl];
    }
    float bpr[8], wp2r[8];
    #pragma unroll
    for (int ct = 0; ct < 8; ct++) {
        bpr[ct]  = bp1[ct*16 + cl];
        wp2r[ct] = Wp2[ct*16 + cl];
    }
    __syncthreads();

    float wsp0 = 0.f, wsp1 = 0.f, wsp2 = 0.f;
    int ntiles = (N + 63) >> 6;
    short* zw = sZ[wv];

    for (int tile = blockIdx.x; tile < ntiles; tile += gridDim.x) {
        int nb = tile * 64 + wv * 16;
        int arow = nb + cl;
        int arowc = arow < N ? arow : N - 1;

        f32x4 acc[3][4];
        #pragma unroll
        for (int p = 0; p < 3; p++)
            #pragma unroll
            for (int ct = 0; ct < 4; ct++)
                acc[p][ct] = (f32x4){0.f,0.f,0.f,0.f};

        #pragma unroll
        for (int ks = 0; ks < 2; ks++) {
            int kb = ks*32 + quad*8;
            bf16x8 fa0 = *(const bf16x8*)&h_bf[(size_t)arowc*DD + kb];
            bf16x8 fa1 = *(const bf16x8*)&a1bf[(size_t)arowc*DD + kb];
            bf16x8 fa2 = *(const bf16x8*)&a2bf[(size_t)arowc*DD + kb];
            #pragma unroll
            for (int ct = 0; ct < 4; ct++) {
                bf16x8 w0 = *(const bf16x8*)&sWb[        (ct*2+ks)*512 + lane*8];
                bf16x8 w1 = *(const bf16x8*)&sWb[4096 +  (ct*2+ks)*512 + lane*8];
                bf16x8 w2 = *(const bf16x8*)&sWb[8192 +  (ct*2+ks)*512 + lane*8];
                acc[0][ct] = __builtin_amdgcn_mfma_f32_16x16x32_bf16(fa0, w0, acc[0][ct], 0,0,0);
                acc[1][ct] = __builtin_amdgcn_mfma_f32_16x16x32_bf16(fa1, w1, acc[1][ct], 0,0,0);
                acc[2][ct] = __builtin_amdgcn_mfma_f32_16x16x32_bf16(fa2, w2, acc[2][ct], 0,0,0);
            }
        }

        // epilogue: bias + ELU, write Z to LDS in A-fragment order
        #pragma unroll
        for (int ct = 0; ct < 4; ct++) {
            int c = ct*16 + cl;
            int obase = (c >> 5)*512 + ((c >> 3) & 3)*128 + (c & 7);
            #pragma unroll
            for (int r = 0; r < 4; r++) {
                int m = quad*4 + r;
                int off = obase + m*8;
                float z0 = acc[0][ct][r] + bid[ct];
                float z1 = elu1(acc[1][ct][r] + bb1r[ct]);
                float z2 = elu1(acc[2][ct][r] + bb2r[ct]);
                zw[off]        = f2bf(z0);
                zw[1024 + off] = f2bf(z1);
                zw[2048 + off] = f2bf(z2);
            }
        }

        float rmask[4];
        #pragma unroll
        for (int r = 0; r < 4; r++)
            rmask[r] = (nb + quad*4 + r) < N ? 1.f : 0.f;

        // GEMM2: t = z @ Wp1 + bp1 ; wsum += tanh(t)*Wp2
        #pragma unroll
        for (int p = 0; p < 3; p++) {
            bf16x8 zA = *(const bf16x8*)&zw[p*1024 +       lane*8];
            bf16x8 zB = *(const bf16x8*)&zw[p*1024 + 512 + lane*8];
            float wsum = 0.f;
            #pragma unroll
            for (int ct = 0; ct < 8; ct++) {
                f32x4 t = (f32x4){0.f,0.f,0.f,0.f};
                bf16x8 u0 = *(const bf16x8*)&sWp[(ct*2+0)*512 + lane*8];
                bf16x8 u1 = *(const bf16x8*)&sWp[(ct*2+1)*512 + lane*8];
                t = __builtin_amdgcn_mfma_f32_16x16x32_bf16(zA, u0, t, 0,0,0);
                t = __builtin_amdgcn_mfma_f32_16x16x32_bf16(zB, u1, t, 0,0,0);
                float s = 0.f;
                #pragma unroll
                for (int r = 0; r < 4; r++)
                    s += fast_tanh(t[r] + bpr[ct]) * rmask[r];
                wsum += s * wp2r[ct];
            }
            if (p == 0)      wsp0 += wsum;
            else if (p == 1) wsp1 += wsum;
            else             wsp2 += wsum;
        }

        // z -> global bf16
        int m8 = lane >> 3;
        int q3 = lane & 7;
        int ks2 = q3 >> 2, qq = q3 & 3;
        #pragma unroll
        for (int pass = 0; pass < 2; pass++) {
            int m = pass*8 + m8;
            int node = nb + m;
            if (node < N) {
                int lo = ks2*512 + (m + qq*16)*8;
                i32x4 v0 = *(const i32x4*)&zw[lo];
                i32x4 v1 = *(const i32x4*)&zw[1024 + lo];
                i32x4 v2 = *(const i32x4*)&zw[2048 + lo];
                char* base1 = (char*)zbuf1 + (size_t)node*256 + ks2*64 + qq*16;
                *(i32x4*)base1 = v1;
                *(i32x4*)(base1 + 128) = v0;
                char* base2 = (char*)zbuf2 + (size_t)node*128 + ks2*64 + qq*16;
                *(i32x4*)base2 = v2;
            }
        }
    }

    #pragma unroll
    for (int off = 32; off >= 1; off >>= 1) {
        wsp0 += __shfl_xor(wsp0, off, 64);
        wsp1 += __shfl_xor(wsp1, off, 64);
        wsp2 += __shfl_xor(wsp2, off, 64);
    }
    if (lane == 0) {
        atomicAdd(&w_acc[0], wsp0);
        atomicAdd(&w_acc[1], wsp1);
        atomicAdd(&w_acc[2], wsp2);
    }
}

__global__ __launch_bounds__(256) void out_kernel(
    const short* __restrict__ zbuf1, const short* __restrict__ zbuf2,
    const float* __restrict__ w_acc, float* __restrict__ out,
    int N, float invN)
{
    int tid = blockIdx.x * 256 + threadIdx.x;
    int n = tid >> 3, part = tid & 7;
    if (n >= N) return;
    float w0 = w_acc[0]*invN, w1 = w_acc[1]*invN, w2 = w_acc[2]*invN;
    float m = fmaxf(w0, fmaxf(w1, w2));
    float e0 = __expf(w0-m), e1 = __expf(w1-m), e2 = __expf(w2-m);
    float s = 1.f/(e0+e1+e2);
    float beta0 = e0*s, beta1 = e1*s, beta2 = e2*s;

    const char* r1 = (const char*)zbuf1 + (size_t)n*256 + part*16;
    const char* r2 = (const char*)zbuf2 + (size_t)n*128 + part*16;
    union U { i32x4 v; short sh[8]; };
    U z1u, z0u, z2u;
    z1u.v = *(const i32x4*)r1;
    z0u.v = *(const i32x4*)(r1 + 128);
    z2u.v = *(const i32x4*)r2;
    float tmp[8];
    #pragma unroll
    for (int j = 0; j < 8; j++)
        tmp[j] = beta0*bf2f(z0u.sh[j]) + beta1*bf2f(z1u.sh[j]) + beta2*bf2f(z2u.sh[j]);
    float4* op = (float4*)(out + (size_t)n*64 + part*8);
    op[0] = (float4){tmp[0],tmp[1],tmp[2],tmp[3]};
    op[1] = (float4){tmp[4],tmp[5],tmp[6],tmp[7]};
}

extern "C" void kernel_launch(void* const* d_in, const int* in_sizes, int n_in,
                              void* d_out, int out_size, void* d_ws, size_t ws_size,
                              hipStream_t stream) {
    const float* h    = (const float*)d_in[0];
    const int*   src1 = (const int*)d_in[1];
    const int*   dst1 = (const int*)d_in[2];
    const int*   src2 = (const int*)d_in[3];
    const int*   dst2 = (const int*)d_in[4];
    const float* W_id = (const float*)d_in[5];
    const float* b_id = (const float*)d_in[6];
    const float* W1   = (const float*)d_in[7];
    const float* b1   = (const float*)d_in[8];
    const float* W2   = (const float*)d_in[9];
    const float* b2   = (const float*)d_in[10];
    const float* Wp1  = (const float*)d_in[11];
    const float* bp1  = (const float*)d_in[12];
    const float* Wp2  = (const float*)d_in[13];
    float* out = (float*)d_out;

    int N = in_sizes[0] / DD;
    int E = in_sizes[1];

    char* p = (char*)d_ws;
    int*   cnt1  = (int*)p;   p += (size_t)N * 4;
    int*   cnt2  = (int*)p;   p += (size_t)N * 4;
    float* w_acc = (float*)p; p += 32;
    int*   off1  = (int*)p;   p += (size_t)N * 4;
    int*   off2  = (int*)p;   p += (size_t)N * 4;
    int*   eidx1 = (int*)p;   p += (size_t)E * 4;
    int*   eidx2 = (int*)p;   p += (size_t)E * 4;
    short* h_bf  = (short*)p; p += (size_t)N * DD * 2;
    short* a1bf  = (short*)p; p += (size_t)N * DD * 2;
    short* a2bf  = (short*)p; p += (size_t)N * DD * 2;
    short* zbuf1 = (short*)p; p += (size_t)N * 128 * 2;
    short* zbuf2 = (short*)p; p += (size_t)N * DD * 2;

    hipMemsetAsync(d_ws, 0, (size_t)2 * N * 4 + 32, stream);

    int Nq = N * 16;                          // N*64/4 float4s
    int hc_threads = Nq > E ? Nq : E;
    hist_conv<<<(hc_threads + 255) / 256, 256, 0, stream>>>(
        dst1, dst2, h, cnt1, cnt2, h_bf, E, Nq);

    scan2<<<2, 1024, 0, stream>>>(cnt1, off1, cnt2, off2, N);

    esort<<<(E + 255) / 256, 256, 0, stream>>>(
        src1, dst1, src2, dst2, off1, off2, eidx1, eidx2, E);

    gather<<<(2 * N + 3) / 4, 256, 0, stream>>>(
        h, cnt1, off1, eidx1, a1bf, cnt2, off2, eidx2, a2bf, N);

    int ntiles = (N + 63) >> 6;
    int fblocks = ntiles < 512 ? ntiles : 512;
    fuse_kernel<<<fblocks, 256, 0, stream>>>(h_bf, W_id, b_id, W1, b1, W2, b2,
                                             Wp1, bp1, Wp2, a1bf, a2bf,
                                             zbuf1, zbuf2, w_acc, N);

    out_kernel<<<(N * 8 + 255) / 256, 256, 0, stream>>>(zbuf1, zbuf2, w_acc, out, N, 1.0f / (float)N);
}

// Round 4
// 675.194 us; speedup vs baseline: 1.4360x; 1.4360x over previous
//
#include <hip/hip_runtime.h>
#include <math.h>

#define DD 64
#define HH 128
#define SCHUNK 2048

typedef __attribute__((ext_vector_type(8))) short bf16x8;
typedef __attribute__((ext_vector_type(4))) short s16x4;
typedef __attribute__((ext_vector_type(4))) float f32x4;
typedef __attribute__((ext_vector_type(4))) int i32x4;

__device__ __forceinline__ short f2bf(float x){
    unsigned u = __builtin_bit_cast(unsigned, x);
    u += 0x7fffu + ((u >> 16) & 1u);          // RTNE
    return (short)(u >> 16);
}
__device__ __forceinline__ float bf2f(short s){
    unsigned u = ((unsigned)(unsigned short)s) << 16;
    return __builtin_bit_cast(float, u);
}
__device__ __forceinline__ float fast_tanh(float x){
    float e = __expf(2.0f * x);
    return 1.0f - 2.0f / (e + 1.0f);
}
__device__ __forceinline__ float elu1(float x){
    return x > 0.0f ? x : (__expf(x) - 1.0f);
}

// histogram of dst (int) for both graphs + h -> bf16 conversion
__global__ __launch_bounds__(256) void hist_conv(
    const int* __restrict__ dst1, const int* __restrict__ dst2,
    const float* __restrict__ h,
    int* __restrict__ cnt1, int* __restrict__ cnt2,
    short* __restrict__ h_bf, int E, int Nq) {
    int tid = blockIdx.x * 256 + threadIdx.x;
    if (tid < E) {
        atomicAdd(&cnt1[dst1[tid]], 1);
        atomicAdd(&cnt2[dst2[tid]], 1);
    }
    if (tid < Nq) {
        float4 v = ((const float4*)h)[tid];
        s16x4 o;
        o[0] = f2bf(v.x); o[1] = f2bf(v.y); o[2] = f2bf(v.z); o[3] = f2bf(v.w);
        ((s16x4*)h_bf)[tid] = o;
    }
}

// ---- 3-phase exclusive scan over both graphs' histograms ----
__global__ __launch_bounds__(256) void scan_reduce(
    const int* __restrict__ c1, const int* __restrict__ c2,
    int* __restrict__ part, int n, int nch) {
    int b = blockIdx.x;
    int g = b >= nch;
    const int* cnt = g ? c2 : c1;
    int cb = b - g * nch;
    int n4 = n >> 2;
    int i4 = cb * (SCHUNK / 4) + threadIdx.x * 2;
    int s = 0;
    #pragma unroll
    for (int k = 0; k < 2; k++) {
        if (i4 + k < n4) {
            int4 v = ((const int4*)cnt)[i4 + k];
            s += v.x + v.y + v.z + v.w;
        }
    }
    #pragma unroll
    for (int off = 32; off >= 1; off >>= 1) s += __shfl_xor(s, off, 64);
    __shared__ int red[4];
    int wv = threadIdx.x >> 6;
    if ((threadIdx.x & 63) == 0) red[wv] = s;
    __syncthreads();
    if (threadIdx.x == 0) part[b] = red[0] + red[1] + red[2] + red[3];
}

__global__ void scan_mid(int* __restrict__ part, int nch) {
    int t = threadIdx.x;
    if (t < 2) {
        int* p = part + t * nch;
        int run = 0;
        for (int i = 0; i < nch; i++) { int v = p[i]; p[i] = run; run += v; }
    }
}

__global__ __launch_bounds__(256) void scan_final(
    const int* __restrict__ c1, int* __restrict__ o1,
    const int* __restrict__ c2, int* __restrict__ o2,
    const int* __restrict__ part, int n, int nch) {
    int b = blockIdx.x;
    int g = b >= nch;
    const int* cnt = g ? c2 : c1;
    int* off       = g ? o2 : o1;
    int cb = b - g * nch;
    int n4 = n >> 2;
    int i4 = cb * (SCHUNK / 4) + threadIdx.x * 2;
    int4 v0 = {0,0,0,0}, v1 = {0,0,0,0};
    if (i4 < n4)     v0 = ((const int4*)cnt)[i4];
    if (i4 + 1 < n4) v1 = ((const int4*)cnt)[i4 + 1];
    int s = v0.x+v0.y+v0.z+v0.w + v1.x+v1.y+v1.z+v1.w;

    __shared__ int ssum[256];
    int tid = threadIdx.x;
    ssum[tid] = s;
    __syncthreads();
    for (int d = 1; d < 256; d <<= 1) {
        int t = (tid >= d) ? ssum[tid - d] : 0;
        __syncthreads();
        ssum[tid] += t;
        __syncthreads();
    }
    int run = part[b] + ssum[tid] - s;   // exclusive prefix for this thread's 8 elems

    int4 o0, o1v;
    o0.x = run; run += v0.x;
    o0.y = run; run += v0.y;
    o0.z = run; run += v0.z;
    o0.w = run; run += v0.w;
    o1v.x = run; run += v1.x;
    o1v.y = run; run += v1.y;
    o1v.z = run; run += v1.z;
    o1v.w = run; run += v1.w;
    if (i4 < n4)     ((int4*)off)[i4]     = o0;
    if (i4 + 1 < n4) ((int4*)off)[i4 + 1] = o1v;
}

// scatter edge src ids into dst-sorted order (4B per edge instead of 256B rows)
__global__ __launch_bounds__(256) void esort(
    const int* __restrict__ src1, const int* __restrict__ dst1,
    const int* __restrict__ src2, const int* __restrict__ dst2,
    int* __restrict__ off1, int* __restrict__ off2,
    int* __restrict__ eidx1, int* __restrict__ eidx2, int E) {
    int e = blockIdx.x * 256 + threadIdx.x;
    if (e >= E) return;
    { int d = dst1[e]; int pos = atomicAdd(&off1[d], 1); eidx1[pos] = src1[e]; }
    { int d = dst2[e]; int pos = atomicAdd(&off2[d], 1); eidx2[pos] = src2[e]; }
}

// wave per (graph,node): sum in-edge h[src] rows in registers, scale by 1/deg, write bf16 row
__global__ __launch_bounds__(256) void gather(
    const float* __restrict__ h,
    const int* __restrict__ cnt1, const int* __restrict__ off1,
    const int* __restrict__ eidx1, short* __restrict__ a1bf,
    const int* __restrict__ cnt2, const int* __restrict__ off2,
    const int* __restrict__ eidx2, short* __restrict__ a2bf, int N) {
    int w = blockIdx.x * 4 + (threadIdx.x >> 6);
    int lane = threadIdx.x & 63;
    if (w >= 2 * N) return;
    int g = w >= N;
    int n = g ? w - N : w;
    const int* cnt  = g ? cnt2  : cnt1;
    const int* off  = g ? off2  : off1;
    const int* eidx = g ? eidx2 : eidx1;
    short* abf      = g ? a2bf  : a1bf;

    int end = off[n];            // off was advanced to end by esort
    int deg = cnt[n];
    int i = end - deg;
    float acc = 0.f;
    for (; i + 1 < end; i += 2) {
        int s0 = eidx[i], s1 = eidx[i + 1];
        float v0 = h[(size_t)s0 * DD + lane];
        float v1 = h[(size_t)s1 * DD + lane];
        acc += v0 + v1;
    }
    if (i < end) acc += h[(size_t)eidx[i] * DD + lane];
    float inv = deg > 0 ? 1.f / (float)deg : 0.f;
    abf[(size_t)n * DD + lane] = f2bf(acc * inv);
}

// MFMA fused kernel: wave = 16 nodes, block = 64 nodes, persistent grid.
__global__ __launch_bounds__(256, 2) void fuse_kernel(
    const short* __restrict__ h_bf,
    const float* __restrict__ W_id, const float* __restrict__ b_id,
    const float* __restrict__ W1, const float* __restrict__ b1,
    const float* __restrict__ W2, const float* __restrict__ b2,
    const float* __restrict__ Wp1, const float* __restrict__ bp1,
    const float* __restrict__ Wp2,
    const short* __restrict__ a1bf, const short* __restrict__ a2bf,
    short* __restrict__ zbuf1, short* __restrict__ zbuf2,
    float* __restrict__ w_acc, int N)
{
    __shared__ __align__(16) short sWb[12288];  // 3 paths * 4 ct * 2 ks * 512
    __shared__ __align__(16) short sWp[8192];   // 8 ct * 2 ks * 512
    __shared__ __align__(16) short sZ[4][3072]; // per wave: 3 paths * 2 ks * 512 (A-frag order)

    for (int i = threadIdx.x; i < 12288; i += 256) {
        int p = i >> 12, r = i & 4095;
        int ct = r >> 10, rr = r & 1023;
        int ks = rr >> 9, q = rr & 511;
        int ln = q >> 3, j = q & 7;
        int c = ct * 16 + (ln & 15);
        int k = ks * 32 + (ln >> 4) * 8 + j;
        int idx = k * DD + c;
        float v = (p == 0) ? W_id[idx] : (p == 1 ? W1[idx] : W2[idx]);
        sWb[i] = f2bf(v);
    }
    for (int i = threadIdx.x; i < 8192; i += 256) {
        int ct = i >> 10, rr = i & 1023;
        int ks = rr >> 9, q = rr & 511;
        int ln = q >> 3, j = q & 7;
        int c = ct * 16 + (ln & 15);
        int k = ks * 32 + (ln >> 4) * 8 + j;
        sWp[i] = f2bf(Wp1[k * HH + c]);
    }

    int lane = threadIdx.x & 63;
    int wv = threadIdx.x >> 6;
    int cl = lane & 15;
    int quad = lane >> 4;

    float bid[4], bb1r[4], bb2r[4];
    #pragma unroll
    for (int ct = 0; ct < 4; ct++) {
        bid[ct]  = b_id[ct*16 + cl];
        bb1r[ct] = b1[ct*16 + cl];
        bb2r[ct] = b2[ct*16 + cl];
    }
    float bpr[8], wp2r[8];
    #pragma unroll
    for (int ct = 0; ct < 8; ct++) {
        bpr[ct]  = bp1[ct*16 + cl];
        wp2r[ct] = Wp2[ct*16 + cl];
    }
    __syncthreads();

    float wsp0 = 0.f, wsp1 = 0.f, wsp2 = 0.f;
    int ntiles = (N + 63) >> 6;
    short* zw = sZ[wv];

    for (int tile = blockIdx.x; tile < ntiles; tile += gridDim.x) {
        int nb = tile * 64 + wv * 16;
        int arow = nb + cl;
        int arowc = arow < N ? arow : N - 1;

        f32x4 acc[3][4];
        #pragma unroll
        for (int p = 0; p < 3; p++)
            #pragma unroll
            for (int ct = 0; ct < 4; ct++)
                acc[p][ct] = (f32x4){0.f,0.f,0.f,0.f};

        #pragma unroll
        for (int ks = 0; ks < 2; ks++) {
            int kb = ks*32 + quad*8;
            bf16x8 fa0 = *(const bf16x8*)&h_bf[(size_t)arowc*DD + kb];
            bf16x8 fa1 = *(const bf16x8*)&a1bf[(size_t)arowc*DD + kb];
            bf16x8 fa2 = *(const bf16x8*)&a2bf[(size_t)arowc*DD + kb];
            #pragma unroll
            for (int ct = 0; ct < 4; ct++) {
                bf16x8 w0 = *(const bf16x8*)&sWb[        (ct*2+ks)*512 + lane*8];
                bf16x8 w1 = *(const bf16x8*)&sWb[4096 +  (ct*2+ks)*512 + lane*8];
                bf16x8 w2 = *(const bf16x8*)&sWb[8192 +  (ct*2+ks)*512 + lane*8];
                acc[0][ct] = __builtin_amdgcn_mfma_f32_16x16x32_bf16(fa0, w0, acc[0][ct], 0,0,0);
                acc[1][ct] = __builtin_amdgcn_mfma_f32_16x16x32_bf16(fa1, w1, acc[1][ct], 0,0,0);
                acc[2][ct] = __builtin_amdgcn_mfma_f32_16x16x32_bf16(fa2, w2, acc[2][ct], 0,0,0);
            }
        }

        // epilogue: bias + ELU, write Z to LDS in A-fragment order
        #pragma unroll
        for (int ct = 0; ct < 4; ct++) {
            int c = ct*16 + cl;
            int obase = (c >> 5)*512 + ((c >> 3) & 3)*128 + (c & 7);
            #pragma unroll
            for (int r = 0; r < 4; r++) {
                int m = quad*4 + r;
                int off = obase + m*8;
                float z0 = acc[0][ct][r] + bid[ct];
                float z1 = elu1(acc[1][ct][r] + bb1r[ct]);
                float z2 = elu1(acc[2][ct][r] + bb2r[ct]);
                zw[off]        = f2bf(z0);
                zw[1024 + off] = f2bf(z1);
                zw[2048 + off] = f2bf(z2);
            }
        }

        float rmask[4];
        #pragma unroll
        for (int r = 0; r < 4; r++)
            rmask[r] = (nb + quad*4 + r) < N ? 1.f : 0.f;

        // GEMM2: t = z @ Wp1 + bp1 ; wsum += tanh(t)*Wp2
        #pragma unroll
        for (int p = 0; p < 3; p++) {
            bf16x8 zA = *(const bf16x8*)&zw[p*1024 +       lane*8];
            bf16x8 zB = *(const bf16x8*)&zw[p*1024 + 512 + lane*8];
            float wsum = 0.f;
            #pragma unroll
            for (int ct = 0; ct < 8; ct++) {
                f32x4 t = (f32x4){0.f,0.f,0.f,0.f};
                bf16x8 u0 = *(const bf16x8*)&sWp[(ct*2+0)*512 + lane*8];
                bf16x8 u1 = *(const bf16x8*)&sWp[(ct*2+1)*512 + lane*8];
                t = __builtin_amdgcn_mfma_f32_16x16x32_bf16(zA, u0, t, 0,0,0);
                t = __builtin_amdgcn_mfma_f32_16x16x32_bf16(zB, u1, t, 0,0,0);
                float s = 0.f;
                #pragma unroll
                for (int r = 0; r < 4; r++)
                    s += fast_tanh(t[r] + bpr[ct]) * rmask[r];
                wsum += s * wp2r[ct];
            }
            if (p == 0)      wsp0 += wsum;
            else if (p == 1) wsp1 += wsum;
            else             wsp2 += wsum;
        }

        // z -> global bf16
        int m8 = lane >> 3;
        int q3 = lane & 7;
        int ks2 = q3 >> 2, qq = q3 & 3;
        #pragma unroll
        for (int pass = 0; pass < 2; pass++) {
            int m = pass*8 + m8;
            int node = nb + m;
            if (node < N) {
                int lo = ks2*512 + (m + qq*16)*8;
                i32x4 v0 = *(const i32x4*)&zw[lo];
                i32x4 v1 = *(const i32x4*)&zw[1024 + lo];
                i32x4 v2 = *(const i32x4*)&zw[2048 + lo];
                char* base1 = (char*)zbuf1 + (size_t)node*256 + ks2*64 + qq*16;
                *(i32x4*)base1 = v1;
                *(i32x4*)(base1 + 128) = v0;
                char* base2 = (char*)zbuf2 + (size_t)node*128 + ks2*64 + qq*16;
                *(i32x4*)base2 = v2;
            }
        }
    }

    #pragma unroll
    for (int off = 32; off >= 1; off >>= 1) {
        wsp0 += __shfl_xor(wsp0, off, 64);
        wsp1 += __shfl_xor(wsp1, off, 64);
        wsp2 += __shfl_xor(wsp2, off, 64);
    }
    if (lane == 0) {
        atomicAdd(&w_acc[0], wsp0);
        atomicAdd(&w_acc[1], wsp1);
        atomicAdd(&w_acc[2], wsp2);
    }
}

__global__ __launch_bounds__(256) void out_kernel(
    const short* __restrict__ zbuf1, const short* __restrict__ zbuf2,
    const float* __restrict__ w_acc, float* __restrict__ out,
    int N, float invN)
{
    int tid = blockIdx.x * 256 + threadIdx.x;
    int n = tid >> 3, part = tid & 7;
    if (n >= N) return;
    float w0 = w_acc[0]*invN, w1 = w_acc[1]*invN, w2 = w_acc[2]*invN;
    float m = fmaxf(w0, fmaxf(w1, w2));
    float e0 = __expf(w0-m), e1 = __expf(w1-m), e2 = __expf(w2-m);
    float s = 1.f/(e0+e1+e2);
    float beta0 = e0*s, beta1 = e1*s, beta2 = e2*s;

    const char* r1 = (const char*)zbuf1 + (size_t)n*256 + part*16;
    const char* r2 = (const char*)zbuf2 + (size_t)n*128 + part*16;
    union U { i32x4 v; short sh[8]; };
    U z1u, z0u, z2u;
    z1u.v = *(const i32x4*)r1;
    z0u.v = *(const i32x4*)(r1 + 128);
    z2u.v = *(const i32x4*)r2;
    float tmp[8];
    #pragma unroll
    for (int j = 0; j < 8; j++)
        tmp[j] = beta0*bf2f(z0u.sh[j]) + beta1*bf2f(z1u.sh[j]) + beta2*bf2f(z2u.sh[j]);
    float4* op = (float4*)(out + (size_t)n*64 + part*8);
    op[0] = (float4){tmp[0],tmp[1],tmp[2],tmp[3]};
    op[1] = (float4){tmp[4],tmp[5],tmp[6],tmp[7]};
}

extern "C" void kernel_launch(void* const* d_in, const int* in_sizes, int n_in,
                              void* d_out, int out_size, void* d_ws, size_t ws_size,
                              hipStream_t stream) {
    const float* h    = (const float*)d_in[0];
    const int*   src1 = (const int*)d_in[1];
    const int*   dst1 = (const int*)d_in[2];
    const int*   src2 = (const int*)d_in[3];
    const int*   dst2 = (const int*)d_in[4];
    const float* W_id = (const float*)d_in[5];
    const float* b_id = (const float*)d_in[6];
    const float* W1   = (const float*)d_in[7];
    const float* b1   = (const float*)d_in[8];
    const float* W2   = (const float*)d_in[9];
    const float* b2   = (const float*)d_in[10];
    const float* Wp1  = (const float*)d_in[11];
    const float* bp1  = (const float*)d_in[12];
    const float* Wp2  = (const float*)d_in[13];
    float* out = (float*)d_out;

    int N = in_sizes[0] / DD;
    int E = in_sizes[1];
    int nch = (N + SCHUNK - 1) / SCHUNK;

    char* p = (char*)d_ws;
    int*   cnt1  = (int*)p;   p += (size_t)N * 4;
    int*   cnt2  = (int*)p;   p += (size_t)N * 4;
    float* w_acc = (float*)p; p += 32;
    int*   part  = (int*)p;   p += (size_t)2 * nch * 4;
    int*   off1  = (int*)p;   p += (size_t)N * 4;
    int*   off2  = (int*)p;   p += (size_t)N * 4;
    int*   eidx1 = (int*)p;   p += (size_t)E * 4;
    int*   eidx2 = (int*)p;   p += (size_t)E * 4;
    short* h_bf  = (short*)p; p += (size_t)N * DD * 2;
    short* a1bf  = (short*)p; p += (size_t)N * DD * 2;
    short* a2bf  = (short*)p; p += (size_t)N * DD * 2;
    short* zbuf1 = (short*)p; p += (size_t)N * 128 * 2;
    short* zbuf2 = (short*)p; p += (size_t)N * DD * 2;

    hipMemsetAsync(d_ws, 0, (size_t)2 * N * 4 + 32, stream);

    int Nq = N * 16;                          // N*64/4 float4s
    int hc_threads = Nq > E ? Nq : E;
    hist_conv<<<(hc_threads + 255) / 256, 256, 0, stream>>>(
        dst1, dst2, h, cnt1, cnt2, h_bf, E, Nq);

    scan_reduce<<<2 * nch, 256, 0, stream>>>(cnt1, cnt2, part, N, nch);
    scan_mid<<<1, 64, 0, stream>>>(part, nch);
    scan_final<<<2 * nch, 256, 0, stream>>>(cnt1, off1, cnt2, off2, part, N, nch);

    esort<<<(E + 255) / 256, 256, 0, stream>>>(
        src1, dst1, src2, dst2, off1, off2, eidx1, eidx2, E);

    gather<<<(2 * N + 3) / 4, 256, 0, stream>>>(
        h, cnt1, off1, eidx1, a1bf, cnt2, off2, eidx2, a2bf, N);

    int ntiles = (N + 63) >> 6;
    int fblocks = ntiles < 512 ? ntiles : 512;
    fuse_kernel<<<fblocks, 256, 0, stream>>>(h_bf, W_id, b_id, W1, b1, W2, b2,
                                             Wp1, bp1, Wp2, a1bf, a2bf,
                                             zbuf1, zbuf2, w_acc, N);

    out_kernel<<<(N * 8 + 255) / 256, 256, 0, stream>>>(zbuf1, zbuf2, w_acc, out, N, 1.0f / (float)N);
}